// Round 7
// baseline (11478.507 us; speedup 1.0000x reference)
//
#include <hip/hip_runtime.h>
#include <hip/hip_bf16.h>
#include <math.h>

#define KSPLIT 16
#define KCHUNK 256
#define BJ 128
#define TSPLIT 2

// ---------------------------------------------------------------------------
// Split-K batched GEMV (proven rounds 1-4).
// ---------------------------------------------------------------------------
__global__ __launch_bounds__(256) void gemv_part_kernel(
    const float* __restrict__ x,
    const float* __restrict__ w0,
    const float* __restrict__ w1,
    const float* __restrict__ w2,
    int jb1, int jb2,
    int off0, int off1, int off2,
    int ncols,
    float* __restrict__ part)
{
  __shared__ float xt[KCHUNK][32];
  int jb = blockIdx.x, ks = blockIdx.y;
  int k0 = ks * KCHUNK;
  const float* w; int colOff, jbase;
  if (jb < jb1)      { w = w0; colOff = off0; jbase = jb * BJ; }
  else if (jb < jb2) { w = w1; colOff = off1; jbase = (jb - jb1) * BJ; }
  else               { w = w2; colOff = off2; jbase = (jb - jb2) * BJ; }
  int tid = threadIdx.x;
  {
    int b = tid & 31, kg = tid >> 5;
    const float* xr = x + (size_t)b * 4096 + k0 + kg * 32;
    #pragma unroll
    for (int i = 0; i < 8; i++) {
      float4 v = *(const float4*)(xr + i * 4);
      int k = kg * 32 + i * 4;
      xt[k + 0][b] = v.x; xt[k + 1][b] = v.y;
      xt[k + 2][b] = v.z; xt[k + 3][b] = v.w;
    }
  }
  __syncthreads();
  int bg = tid & 7, jg = tid >> 3;
  const float* wb = w + (size_t)(jbase + jg * 4) * 4096 + k0;
  float acc[4][4] = {};
  #pragma unroll 4
  for (int k4 = 0; k4 < KCHUNK / 4; k4++) {
    float wr[4][4], xv[4][4];
    #pragma unroll
    for (int jj = 0; jj < 4; jj++) {
      float4 t = *(const float4*)(wb + (size_t)jj * 4096 + k4 * 4);
      wr[jj][0] = t.x; wr[jj][1] = t.y; wr[jj][2] = t.z; wr[jj][3] = t.w;
    }
    #pragma unroll
    for (int c = 0; c < 4; c++) {
      float4 t = *(const float4*)(&xt[k4 * 4 + c][bg * 4]);
      xv[c][0] = t.x; xv[c][1] = t.y; xv[c][2] = t.z; xv[c][3] = t.w;
    }
    #pragma unroll
    for (int jj = 0; jj < 4; jj++)
      #pragma unroll
      for (int bb = 0; bb < 4; bb++)
        acc[jj][bb] += wr[jj][0] * xv[0][bb] + wr[jj][1] * xv[1][bb]
                     + wr[jj][2] * xv[2][bb] + wr[jj][3] * xv[3][bb];
  }
  #pragma unroll
  for (int jj = 0; jj < 4; jj++) {
    int col = colOff + jbase + jg * 4 + jj;
    #pragma unroll
    for (int bb = 0; bb < 4; bb++) {
      int b_ = bg * 4 + bb;
      part[((size_t)ks * 32 + b_) * ncols + col] = acc[jj][bb];
    }
  }
}

// ---------------------------------------------------------------------------
// Reduce split-K partials; RoPE (proven rounds 1-4).
// ---------------------------------------------------------------------------
__global__ __launch_bounds__(256) void reduce_rope_kernel(
    const float* __restrict__ part, int ncols,
    const float* __restrict__ cosv, const float* __restrict__ sinv,
    int ropeEnd, float* __restrict__ outb)
{
  int idx = blockIdx.x * 256 + threadIdx.x;
  int np = ncols >> 1;
  int b = idx / np;
  int cp = idx - b * np;
  int col = cp * 2;
  float e = 0.f, o = 0.f;
  #pragma unroll
  for (int ks = 0; ks < KSPLIT; ks++) {
    float2 v = *(const float2*)(part + ((size_t)ks * 32 + b) * ncols + col);
    e += v.x; o += v.y;
  }
  if (col < ropeEnd) {
    int fi = (col & 127) >> 1;
    float c = cosv[fi], s = sinv[fi];
    float ne = e * c - o * s;
    float no = e * s + o * c;
    e = ne; o = no;
  }
  *(float2*)(outb + (size_t)b * ncols + col) = make_float2(e, o);
}

// ===========================================================================
// SUSPECT PATH (rounds 5/6, verbatim) — under bisection this round.
// ===========================================================================
__global__ __launch_bounds__(256, 8) void qk_kernel(
    const float* __restrict__ qkv,
    const float* __restrict__ cache_k,
    const int* __restrict__ spp,
    float* __restrict__ s_ws)
{
  int bid = blockIdx.x;
  int ts = bid & 7, h = (bid >> 3) & 7, b = bid >> 6;
  int sp = *spp;
  const float scale = 0.088388347648318447f;
  int tid = threadIdx.x;
  int wave = tid >> 6, lane = tid & 63;
  int tl = lane >> 5, dq = lane & 31;
  int tbase = ts * 256 + wave * 64;

  float4 qreg[4];
  {
    const float* qb = qkv + (size_t)b * 6144 + h * 512 + dq * 4;
    #pragma unroll
    for (int r = 0; r < 4; r++) {
      float4 q = *(const float4*)(qb + r * 128);
      qreg[r] = make_float4(q.x * scale, q.y * scale, q.z * scale, q.w * scale);
    }
  }
  const float* Krow = cache_k + (size_t)(b * 2048 + tbase + tl) * 1024 + h * 128 + dq * 4;
  float* srow = s_ws + (size_t)(b * 8 + h) * 8192;

  float4 buf[4];
  #pragma unroll
  for (int g = 0; g < 3; g++) buf[g] = *(const float4*)(Krow + (size_t)g * 2048);
  #pragma unroll 8
  for (int g = 0; g < 32; g++) {
    float4 kv = buf[g & 3];
    if (g + 3 < 32) buf[(g + 3) & 3] = *(const float4*)(Krow + (size_t)(g + 3) * 2048);
    float s0 = kv.x*qreg[0].x + kv.y*qreg[0].y + kv.z*qreg[0].z + kv.w*qreg[0].w;
    float s1 = kv.x*qreg[1].x + kv.y*qreg[1].y + kv.z*qreg[1].z + kv.w*qreg[1].w;
    float s2 = kv.x*qreg[2].x + kv.y*qreg[2].y + kv.z*qreg[2].z + kv.w*qreg[2].w;
    float s3 = kv.x*qreg[3].x + kv.y*qreg[3].y + kv.z*qreg[3].z + kv.w*qreg[3].w;
    #pragma unroll
    for (int off = 1; off <= 16; off <<= 1) {
      s0 += __shfl_xor(s0, off);
      s1 += __shfl_xor(s1, off);
      s2 += __shfl_xor(s2, off);
      s3 += __shfl_xor(s3, off);
    }
    int t = tbase + g * 2 + tl;
    if (dq == 0 && t != sp)
      *(float4*)(srow + (size_t)t * 4) = make_float4(s0, s1, s2, s3);
  }
  if (wave == 0 && (sp >> 8) == ts) {
    float4 kn4 = *(const float4*)(qkv + (size_t)b * 6144 + 4096 + h * 128 + dq * 4);
    float a[4];
    #pragma unroll
    for (int r = 0; r < 4; r++) {
      float a_ = kn4.x*qreg[r].x + kn4.y*qreg[r].y + kn4.z*qreg[r].z + kn4.w*qreg[r].w;
      #pragma unroll
      for (int off = 1; off <= 16; off <<= 1) a_ += __shfl_xor(a_, off);
      a[r] = a_;
    }
    if (lane == 0)
      *(float4*)(srow + (size_t)sp * 4) = make_float4(a[0], a[1], a[2], a[3]);
  }
}

__global__ __launch_bounds__(256) void softmax_kernel(float* __restrict__ s_ws)
{
  __shared__ float wred[4][4];
  int bh = blockIdx.x;
  float* srow = s_ws + (size_t)bh * 8192;
  int tid = threadIdx.x, wave = tid >> 6, lane = tid & 63;
  float4 v[8];
  float pm[4] = {-INFINITY, -INFINITY, -INFINITY, -INFINITY};
  #pragma unroll
  for (int k = 0; k < 8; k++) {
    v[k] = *(const float4*)(srow + (size_t)(k * 256 + tid) * 4);
    pm[0] = fmaxf(pm[0], v[k].x); pm[1] = fmaxf(pm[1], v[k].y);
    pm[2] = fmaxf(pm[2], v[k].z); pm[3] = fmaxf(pm[3], v[k].w);
  }
  #pragma unroll
  for (int r = 0; r < 4; r++)
    #pragma unroll
    for (int off = 32; off >= 1; off >>= 1)
      pm[r] = fmaxf(pm[r], __shfl_xor(pm[r], off));
  if (lane == 0) {
    wred[wave][0] = pm[0]; wred[wave][1] = pm[1];
    wred[wave][2] = pm[2]; wred[wave][3] = pm[3];
  }
  __syncthreads();
  float m4[4];
  #pragma unroll
  for (int r = 0; r < 4; r++)
    m4[r] = fmaxf(fmaxf(wred[0][r], wred[1][r]), fmaxf(wred[2][r], wred[3][r]));
  __syncthreads();
  float ps[4] = {0.f, 0.f, 0.f, 0.f};
  #pragma unroll
  for (int k = 0; k < 8; k++) {
    v[k].x = __expf(v[k].x - m4[0]); ps[0] += v[k].x;
    v[k].y = __expf(v[k].y - m4[1]); ps[1] += v[k].y;
    v[k].z = __expf(v[k].z - m4[2]); ps[2] += v[k].z;
    v[k].w = __expf(v[k].w - m4[3]); ps[3] += v[k].w;
  }
  #pragma unroll
  for (int r = 0; r < 4; r++)
    #pragma unroll
    for (int off = 32; off >= 1; off >>= 1)
      ps[r] += __shfl_xor(ps[r], off);
  if (lane == 0) {
    wred[wave][0] = ps[0]; wred[wave][1] = ps[1];
    wred[wave][2] = ps[2]; wred[wave][3] = ps[3];
  }
  __syncthreads();
  float inv[4];
  #pragma unroll
  for (int r = 0; r < 4; r++)
    inv[r] = 1.f / (wred[0][r] + wred[1][r] + wred[2][r] + wred[3][r]);
  #pragma unroll
  for (int k = 0; k < 8; k++) {
    v[k].x *= inv[0]; v[k].y *= inv[1]; v[k].z *= inv[2]; v[k].w *= inv[3];
    *(float4*)(srow + (size_t)(k * 256 + tid) * 4) = v[k];
  }
}

__global__ __launch_bounds__(256, 8) void pv_kernel(
    const float* __restrict__ p_ws,
    const float* __restrict__ cache_v,
    const int* __restrict__ spp,
    float* __restrict__ pv_part)
{
  int bid = blockIdx.x;
  int ts = bid & 7, h = (bid >> 3) & 7, b = bid >> 6;
  int sp = *spp;
  int tid = threadIdx.x, wave = tid >> 6, lane = tid & 63;
  int half = lane >> 5, dq = lane & 31;
  int tbase = ts * 256 + wave * 64;
  const float* Vrow = cache_v + (size_t)(b * 2048 + tbase + half) * 1024 + h * 128 + dq * 4;
  const float* prow = p_ws + (size_t)(b * 8 + h) * 8192;

  float4 vbuf[4];
  #pragma unroll
  for (int g = 0; g < 3; g++) vbuf[g] = *(const float4*)(Vrow + (size_t)g * 2048);
  float o[4][4] = {};
  #pragma unroll 8
  for (int g = 0; g < 32; g++) {
    float4 vv = vbuf[g & 3];
    if (g + 3 < 32) vbuf[(g + 3) & 3] = *(const float4*)(Vrow + (size_t)(g + 3) * 2048);
    int t = tbase + g * 2 + half;
    float4 pp = *(const float4*)(prow + (size_t)t * 4);
    if (t == sp) pp = make_float4(0.f, 0.f, 0.f, 0.f);
    o[0][0] += pp.x * vv.x; o[0][1] += pp.x * vv.y;
    o[0][2] += pp.x * vv.z; o[0][3] += pp.x * vv.w;
    o[1][0] += pp.y * vv.x; o[1][1] += pp.y * vv.y;
    o[1][2] += pp.y * vv.z; o[1][3] += pp.y * vv.w;
    o[2][0] += pp.z * vv.x; o[2][1] += pp.z * vv.y;
    o[2][2] += pp.z * vv.z; o[2][3] += pp.z * vv.w;
    o[3][0] += pp.w * vv.x; o[3][1] += pp.w * vv.y;
    o[3][2] += pp.w * vv.z; o[3][3] += pp.w * vv.w;
  }
  #pragma unroll
  for (int r = 0; r < 4; r++)
    #pragma unroll
    for (int j = 0; j < 4; j++) o[r][j] += __shfl_xor(o[r][j], 32);
  if (half == 0) {
    float* pb = pv_part + (size_t)(((ts * 32 + b) * 8 + h) * 4) * 128 + dq * 4;
    #pragma unroll
    for (int r = 0; r < 4; r++)
      *(float4*)(pb + r * 128) = make_float4(o[r][0], o[r][1], o[r][2], o[r][3]);
  }
}

__global__ __launch_bounds__(256) void pv_combine_kernel(
    const float* __restrict__ pv_part,
    const float* __restrict__ p_ws,
    const float* __restrict__ qkv,
    const int* __restrict__ spp,
    float* __restrict__ attn)
{
  int idx = blockIdx.x * 256 + threadIdx.x;
  int d = idx & 127;
  int r = (idx >> 7) & 3;
  int h = (idx >> 9) & 7;
  int b = idx >> 12;
  float acc = 0.f;
  #pragma unroll
  for (int ts = 0; ts < 8; ts++)
    acc += pv_part[(size_t)(((ts * 32 + b) * 8 + h) * 4 + r) * 128 + d];
  int sp = *spp;
  float psp = p_ws[(size_t)(b * 8 + h) * 8192 + (size_t)sp * 4 + r];
  float vn  = qkv[(size_t)b * 6144 + 5120 + h * 128 + d];
  attn[idx] = acc + psp * vn;
}

// ===========================================================================
// NAIVE REFERENCES (independent implementations, b < 16 only)
// ===========================================================================
__global__ __launch_bounds__(256) void naive_qk_kernel(
    const float* __restrict__ qkv, const float* __restrict__ cache_k,
    const int* __restrict__ spp, float* __restrict__ s_ref)
{
  int idx = blockIdx.x * 256 + threadIdx.x;   // 16*8*2048 = 262144
  int t = idx & 2047, h = (idx >> 11) & 7, b = idx >> 14;
  int sp = *spp;
  const float scale = 0.088388347648318447f;
  const float* krow = (t == sp)
      ? qkv + (size_t)b * 6144 + 4096 + h * 128
      : cache_k + (size_t)(b * 2048 + t) * 1024 + h * 128;
  const float* qb = qkv + (size_t)b * 6144 + h * 512;
  for (int r = 0; r < 4; r++) {
    float acc = 0.f;
    for (int d = 0; d < 128; d++) acc += krow[d] * qb[r * 128 + d];
    s_ref[((size_t)(b * 8 + h) * 2048 + t) * 4 + r] = acc * scale;
  }
}

__global__ __launch_bounds__(256) void naive_sm_kernel(float* __restrict__ s_ref)
{
  int idx = blockIdx.x * 256 + threadIdx.x;   // 512 = 16*8*4
  if (idx >= 512) return;
  int r = idx & 3, h = (idx >> 2) & 7, b = idx >> 5;
  float* col = s_ref + (size_t)(b * 8 + h) * 8192 + r;
  float m = -INFINITY;
  for (int t = 0; t < 2048; t++) m = fmaxf(m, col[t * 4]);
  float l = 0.f;
  for (int t = 0; t < 2048; t++) l += __expf(col[t * 4] - m);
  float inv = 1.f / l;
  for (int t = 0; t < 2048; t++) col[t * 4] = __expf(col[t * 4] - m) * inv;
}

__global__ __launch_bounds__(256) void naive_pv_kernel(
    const float* __restrict__ p_ws, const float* __restrict__ cache_v,
    const int* __restrict__ spp, float* __restrict__ pv_ref)
{
  int idx = blockIdx.x * 256 + threadIdx.x;   // 65536 = 16*8*4*128
  int d = idx & 127, r = (idx >> 7) & 3, h = (idx >> 9) & 7, b = idx >> 12;
  int sp = *spp;
  const float* prow = p_ws + (size_t)(b * 8 + h) * 8192 + r;
  const float* vcol = cache_v + (size_t)b * 2048 * 1024 + h * 128 + d;
  float acc = 0.f;
  for (int t = 0; t < 2048; t++) {
    float p = (t == sp) ? 0.f : prow[t * 4];
    acc += p * vcol[(size_t)t * 1024];
  }
  pv_ref[idx] = acc;
}

// ===========================================================================
// PROBES — spin ~1.7 ms if max|diff| > tol (duration-encoded verdict).
// ===========================================================================
__device__ __forceinline__ void spin_if(float d, float tol, float* sink)
{
  #pragma unroll
  for (int off = 32; off >= 1; off >>= 1) d = fmaxf(d, __shfl_xor(d, off));
  if ((threadIdx.x & 63) == 0 && d > tol) {
    float x = d;
    for (int k = 0; k < (1 << 20); k++) x = __builtin_fmaf(x, 1.0000001f, 1e-30f);
    if (x > 1e30f) *sink = x;   // never true; keeps the loop alive
  }
}

__global__ __launch_bounds__(256) void probe_qk_kernel(
    const float* __restrict__ a, const float* __restrict__ b2,
    int n, float tol, float* sink)
{
  float d = 0.f;
  for (int i = blockIdx.x * 256 + threadIdx.x; i < n; i += gridDim.x * 256)
    d = fmaxf(d, fabsf(a[i] - b2[i]));
  spin_if(d, tol, sink);
}

__global__ __launch_bounds__(256) void probe_sm_kernel(
    const float* __restrict__ a, const float* __restrict__ b2,
    int n, float tol, float* sink)
{
  float d = 0.f;
  for (int i = blockIdx.x * 256 + threadIdx.x; i < n; i += gridDim.x * 256)
    d = fmaxf(d, fabsf(a[i] - b2[i]));
  spin_if(d, tol, sink);
}

__global__ __launch_bounds__(256) void probe_pv_kernel(
    const float* __restrict__ pv_part, const float* __restrict__ pv_ref,
    float tol, float* sink)
{
  int idx = blockIdx.x * 256 + threadIdx.x;   // 65536
  int d = idx & 127, r = (idx >> 7) & 3, h = (idx >> 9) & 7, b = idx >> 12;
  float acc = 0.f;
  #pragma unroll
  for (int ts = 0; ts < 8; ts++)
    acc += pv_part[(size_t)(((ts * 32 + b) * 8 + h) * 4 + r) * 128 + d];
  spin_if(fabsf(acc - pv_ref[idx]), tol, sink);
}

__global__ __launch_bounds__(256) void probe_attn_kernel(
    const float* __restrict__ a, const float* __restrict__ b2,
    int n, float tol, float* sink)
{
  float d = 0.f;
  for (int i = blockIdx.x * 256 + threadIdx.x; i < n; i += gridDim.x * 256)
    d = fmaxf(d, fabsf(a[i] - b2[i]));
  spin_if(d, tol, sink);
}

// ===========================================================================
// PROVEN PATH — round-4 fused attention (verbatim, passed at absmax 2.44e-4)
// ===========================================================================
__global__ __launch_bounds__(256, 2) void attn_kernel(
    const float* __restrict__ qkv,
    const float* __restrict__ cache_k,
    const float* __restrict__ cache_v,
    const int* __restrict__ spp,
    float* __restrict__ attn_part)
{
  __shared__ float sbuf[4][64][4];
  __shared__ float kn_s[128], vn_s[128];
  __shared__ float comb[4][520];

  int bid = blockIdx.x;
  int ts = bid & (TSPLIT - 1), h = (bid >> 1) & 7, b = bid >> 4;
  int sp = *spp;
  const float scale = 0.088388347648318447f;
  int tid = threadIdx.x;

  if (tid < 128)      kn_s[tid]       = qkv[(size_t)b * 6144 + 4096 + h * 128 + tid];
  else                vn_s[tid - 128] = qkv[(size_t)b * 6144 + 5120 + h * 128 + tid - 128];
  __syncthreads();

  int wave = tid >> 6, lane = tid & 63;
  int half = lane >> 5, dq = lane & 31;
  int tl = lane & 7,  dg = lane >> 3;
  int base0 = ts * 1024 + wave * 256;
  const float* Kb = cache_k + (size_t)b * 2048 * 1024 + h * 128;
  const float* Vb = cache_v + (size_t)b * 2048 * 1024 + h * 128;

  float4 qreg[4][4];
  {
    const float* qb = qkv + (size_t)b * 6144 + h * 512;
    #pragma unroll
    for (int r = 0; r < 4; r++)
      #pragma unroll
      for (int i = 0; i < 4; i++)
        qreg[r][i] = *(const float4*)(qb + r * 128 + dg * 4 + i * 32);
  }

  float m[4]    = {-INFINITY, -INFINITY, -INFINITY, -INFINITY};
  float lsum[4] = {0.f, 0.f, 0.f, 0.f};
  float o[4][4] = {};

  for (int c = 0; c < 4; c++) {
    int tbase = base0 + c * 64;
    {
      const float* Krow = Kb + (size_t)(tbase + tl) * 1024 + dg * 4;
      float4 kbuf[3][4];
      auto LOADG = [&](int g, int buf) {
        #pragma unroll
        for (int i = 0; i < 4; i++)
          kbuf[buf][i] = *(const float4*)(Krow + (size_t)g * 8192 + i * 32);
      };
      LOADG(0, 0); LOADG(1, 1);
      #pragma unroll
      for (int g = 0; g < 8; g++) {
        if (g + 2 < 8) LOADG(g + 2, (g + 2) % 3);
        const float4* kb = kbuf[g % 3];
        float sp4[4] = {0.f, 0.f, 0.f, 0.f};
        #pragma unroll
        for (int i = 0; i < 4; i++)
          #pragma unroll
          for (int r = 0; r < 4; r++)
            sp4[r] += kb[i].x * qreg[r][i].x + kb[i].y * qreg[r][i].y
                    + kb[i].z * qreg[r][i].z + kb[i].w * qreg[r][i].w;
        #pragma unroll
        for (int r = 0; r < 4; r++) {
          sp4[r] += __shfl_xor(sp4[r], 8);
          sp4[r] += __shfl_xor(sp4[r], 16);
          sp4[r] += __shfl_xor(sp4[r], 32);
        }
        if (dg == 0)
          *(float4*)(&sbuf[wave][g * 8 + tl][0]) = make_float4(
              sp4[0] * scale, sp4[1] * scale, sp4[2] * scale, sp4[3] * scale);
      }
    }
    {
      int t = tbase + lane;
      float4 sv = *(const float4*)(&sbuf[wave][lane][0]);
      float s4[4] = {sv.x, sv.y, sv.z, sv.w};
      if (t >= sp) { s4[0] = s4[1] = s4[2] = s4[3] = -INFINITY; }
      float pv[4];
      #pragma unroll
      for (int r = 0; r < 4; r++) {
        float cm = s4[r];
        #pragma unroll
        for (int off = 32; off >= 1; off >>= 1) cm = fmaxf(cm, __shfl_xor(cm, off));
        float nm = fmaxf(m[r], cm);
        float alpha, p;
        if (nm == -INFINITY) { alpha = 1.f; p = 0.f; }
        else {
          alpha = __expf(m[r] - nm);
          p = (s4[r] == -INFINITY) ? 0.f : __expf(s4[r] - nm);
        }
        m[r] = nm;
        lsum[r] = lsum[r] * alpha + p;
        #pragma unroll
        for (int j = 0; j < 4; j++) o[r][j] *= alpha;
        pv[r] = p;
      }
      *(float4*)(&sbuf[wave][lane][0]) = make_float4(pv[0], pv[1], pv[2], pv[3]);
    }
    {
      const float* Vsrc = Vb + (size_t)(tbase + half) * 1024 + dq * 4;
      float4 vbuf[3][4];
      auto LOADV = [&](int G, int buf) {
        #pragma unroll
        for (int j = 0; j < 4; j++)
          vbuf[buf][j] = *(const float4*)(Vsrc + (size_t)(G * 8 + j * 2) * 1024);
      };
      LOADV(0, 0); LOADV(1, 1);
      #pragma unroll
      for (int G = 0; G < 8; G++) {
        if (G + 2 < 8) LOADV(G + 2, (G + 2) % 3);
        #pragma unroll
        for (int j = 0; j < 4; j++) {
          float4 vv = vbuf[G % 3][j];
          float4 pp = *(const float4*)(&sbuf[wave][G * 8 + j * 2 + half][0]);
          o[0][0] += pp.x * vv.x; o[0][1] += pp.x * vv.y;
          o[0][2] += pp.x * vv.z; o[0][3] += pp.x * vv.w;
          o[1][0] += pp.y * vv.x; o[1][1] += pp.y * vv.y;
          o[1][2] += pp.y * vv.z; o[1][3] += pp.y * vv.w;
          o[2][0] += pp.z * vv.x; o[2][1] += pp.z * vv.y;
          o[2][2] += pp.z * vv.z; o[2][3] += pp.z * vv.w;
          o[3][0] += pp.w * vv.x; o[3][1] += pp.w * vv.y;
          o[3][2] += pp.w * vv.z; o[3][3] += pp.w * vv.w;
        }
      }
    }
  }

  if (wave == 0 && sp >= ts * 1024 && sp < ts * 1024 + 1024) {
    float4 kn4[4];
    #pragma unroll
    for (int i = 0; i < 4; i++)
      kn4[i] = *(const float4*)(&kn_s[dg * 4 + i * 32]);
    float sNew[4];
    #pragma unroll
    for (int r = 0; r < 4; r++) {
      float a = 0.f;
      #pragma unroll
      for (int i = 0; i < 4; i++)
        a += kn4[i].x * qreg[r][i].x + kn4[i].y * qreg[r][i].y
           + kn4[i].z * qreg[r][i].z + kn4[i].w * qreg[r][i].w;
      a += __shfl_xor(a, 8);
      a += __shfl_xor(a, 16);
      a += __shfl_xor(a, 32);
      sNew[r] = a * scale;
    }
    #pragma unroll
    for (int r = 0; r < 4; r++) {
      float nm = fmaxf(m[r], sNew[r]);
      float alpha = (m[r] == -INFINITY) ? 0.f : __expf(m[r] - nm);
      float p = __expf(sNew[r] - nm);
      m[r] = nm;
      lsum[r] = lsum[r] * alpha + ((lane == 0) ? p : 0.f);
      float sel = (half == 0) ? p : 0.f;
      #pragma unroll
      for (int j = 0; j < 4; j++)
        o[r][j] = o[r][j] * alpha + sel * vn_s[dq * 4 + j];
    }
  }

  #pragma unroll
  for (int r = 0; r < 4; r++) {
    float L = lsum[r];
    #pragma unroll
    for (int off = 32; off >= 1; off >>= 1) L += __shfl_xor(L, off);
    #pragma unroll
    for (int j = 0; j < 4; j++) o[r][j] += __shfl_xor(o[r][j], 32);
    if (lane == 0) { comb[wave][512 + r] = m[r]; comb[wave][516 + r] = L; }
    if (half == 0) {
      #pragma unroll
      for (int j = 0; j < 4; j++) comb[wave][r * 128 + dq * 4 + j] = o[r][j];
    }
  }
  __syncthreads();
  {
    int r = tid >> 6, dp = tid & 63;
    float gm = fmaxf(fmaxf(comb[0][512 + r], comb[1][512 + r]),
                     fmaxf(comb[2][512 + r], comb[3][512 + r]));
    float L = 0.f, O0 = 0.f, O1 = 0.f;
    #pragma unroll
    for (int wv = 0; wv < 4; wv++) {
      float mm = comb[wv][512 + r];
      float al = (mm == -INFINITY) ? 0.f : __expf(mm - gm);
      L  += comb[wv][516 + r] * al;
      O0 += comb[wv][r * 128 + dp * 2]     * al;
      O1 += comb[wv][r * 128 + dp * 2 + 1] * al;
    }
    float* ap = attn_part + ((((size_t)ts * 32 + b) * 8 + h) * 4 + r) * 130;
    if (dp == 0) { ap[0] = gm; ap[1] = L; }
    ap[2 + dp * 2] = O0;
    ap[3 + dp * 2] = O1;
  }
}

__global__ __launch_bounds__(256) void attn_combine_kernel(
    const float* __restrict__ attn_part, float* __restrict__ attn)
{
  int idx = blockIdx.x * 256 + threadIdx.x;
  int d = idx & 127;
  int r = (idx >> 7) & 3;
  int h = (idx >> 9) & 7;
  int b = idx >> 12;
  float mv[TSPLIT], lv[TSPLIT], ov[TSPLIT];
  float gm = -INFINITY;
  #pragma unroll
  for (int ts = 0; ts < TSPLIT; ts++) {
    const float* ap = attn_part + (((size_t)(ts * 32 + b) * 8 + h) * 4 + r) * 130;
    mv[ts] = ap[0]; lv[ts] = ap[1]; ov[ts] = ap[2 + d];
    gm = fmaxf(gm, mv[ts]);
  }
  float L = 0.f, O = 0.f;
  #pragma unroll
  for (int ts = 0; ts < TSPLIT; ts++) {
    float al = (mv[ts] == -INFINITY) ? 0.f : __expf(mv[ts] - gm);
    L += lv[ts] * al;
    O += ov[ts] * al;
  }
  attn[idx] = O / L;
}

extern "C" void kernel_launch(void* const* d_in, const int* in_sizes, int n_in,
                              void* d_out, int out_size, void* d_ws, size_t ws_size,
                              hipStream_t stream)
{
  const float* x   = (const float*)d_in[0];
  const float* wq  = (const float*)d_in[1];
  const float* wk  = (const float*)d_in[2];
  const float* wv  = (const float*)d_in[3];
  const float* wo  = (const float*)d_in[4];
  const float* fc  = (const float*)d_in[5];
  const float* fs  = (const float*)d_in[6];
  const float* ck  = (const float*)d_in[7];
  const float* cv  = (const float*)d_in[8];
  const int*   spp = (const int*)d_in[9];
  float* out = (float*)d_out;

  // Workspace (floats). High-water 3,670,017 f = 14.68 MB <= proven 14.96 MB.
  float* ws = (float*)d_ws;
  float* qkv_part  = ws;              // L1-L2
  float* s_ws      = ws;              // suspect-path scores/p (after L2)
  float* s_ref     = ws + 2097152;    // naive b<16 scores/p
  float* pv_part   = ws + 2097152;    // after s_ref dead
  float* attn_part = ws + 2097152;    // r4 path, after pv_part dead
  float* out_part  = ws;              // after s_ws dead
  float* qkvbuf    = ws + 3145728;
  float* attn_new  = ws + 3342336;    // suspect-path attention out (131072)
  float* pv_ref    = ws + 3473408;    // naive pv (65536)
  float* attnbuf2  = ws + 3538944;    // r4 attention out (131072) -> feeds WO
  float* sink      = ws + 3670016;    // probe DCE-blocker (1)

  gemv_part_kernel<<<dim3(48, KSPLIT), 256, 0, stream>>>(
      x, wq, wk, wv, 32, 40, 0, 4096, 5120, 6144, qkv_part);
  reduce_rope_kernel<<<384, 256, 0, stream>>>(qkv_part, 6144, fc, fs, 5120, qkvbuf);

  // --- suspect path + stage-by-stage probes (compare range: b < 16) ---
  qk_kernel<<<2048, 256, 0, stream>>>(qkvbuf, ck, spp, s_ws);
  naive_qk_kernel<<<1024, 256, 0, stream>>>(qkvbuf, ck, spp, s_ref);
  probe_qk_kernel<<<512, 256, 0, stream>>>(s_ws, s_ref, 1048576, 2e-3f, sink);
  softmax_kernel<<<256, 256, 0, stream>>>(s_ws);
  naive_sm_kernel<<<2, 256, 0, stream>>>(s_ref);
  probe_sm_kernel<<<512, 256, 0, stream>>>(s_ws, s_ref, 1048576, 3e-4f, sink);
  pv_kernel<<<2048, 256, 0, stream>>>(s_ws, cv, spp, pv_part);
  naive_pv_kernel<<<256, 256, 0, stream>>>(s_ws, cv, spp, pv_ref);
  probe_pv_kernel<<<256, 256, 0, stream>>>(pv_part, pv_ref, 1e-3f, sink);
  pv_combine_kernel<<<512, 256, 0, stream>>>(pv_part, s_ws, qkvbuf, spp, attn_new);

  // --- proven round-4 path (authoritative output) ---
  attn_kernel<<<512, 256, 0, stream>>>(qkvbuf, ck, cv, spp, attn_part);
  attn_combine_kernel<<<512, 256, 0, stream>>>(attn_part, attnbuf2);
  probe_attn_kernel<<<512, 256, 0, stream>>>(attn_new, attnbuf2, 131072, 1e-3f, sink);

  gemv_part_kernel<<<dim3(32, KSPLIT), 256, 0, stream>>>(
      attnbuf2, wo, wo, wo, 32, 32, 0, 0, 0, 4096, out_part);
  reduce_rope_kernel<<<256, 256, 0, stream>>>(out_part, 4096, fc, fs, 0, out);
}

// Round 8
// 360.183 us; speedup vs baseline: 31.8685x; 31.8685x over previous
//
#include <hip/hip_runtime.h>
#include <hip/hip_bf16.h>
#include <math.h>

#define KSPLIT 16
#define KCHUNK 256
#define BJ 128

// ---------------------------------------------------------------------------
// Split-K batched GEMV: part[ks][b][col] = sum_{k in chunk ks} x[b][k]*w[col][k]
// ---------------------------------------------------------------------------
__global__ __launch_bounds__(256) void gemv_part_kernel(
    const float* __restrict__ x,
    const float* __restrict__ w0,
    const float* __restrict__ w1,
    const float* __restrict__ w2,
    int jb1, int jb2,
    int off0, int off1, int off2,
    int ncols,
    float* __restrict__ part)
{
  __shared__ float xt[KCHUNK][32];
  int jb = blockIdx.x, ks = blockIdx.y;
  int k0 = ks * KCHUNK;
  const float* w; int colOff, jbase;
  if (jb < jb1)      { w = w0; colOff = off0; jbase = jb * BJ; }
  else if (jb < jb2) { w = w1; colOff = off1; jbase = (jb - jb1) * BJ; }
  else               { w = w2; colOff = off2; jbase = (jb - jb2) * BJ; }
  int tid = threadIdx.x;
  {
    int b = tid & 31, kg = tid >> 5;
    const float* xr = x + (size_t)b * 4096 + k0 + kg * 32;
    #pragma unroll
    for (int i = 0; i < 8; i++) {
      float4 v = *(const float4*)(xr + i * 4);
      int k = kg * 32 + i * 4;
      xt[k + 0][b] = v.x; xt[k + 1][b] = v.y;
      xt[k + 2][b] = v.z; xt[k + 3][b] = v.w;
    }
  }
  __syncthreads();
  int bg = tid & 7, jg = tid >> 3;
  const float* wb = w + (size_t)(jbase + jg * 4) * 4096 + k0;
  float acc[4][4] = {};
  #pragma unroll 4
  for (int k4 = 0; k4 < KCHUNK / 4; k4++) {
    float wr[4][4], xv[4][4];
    #pragma unroll
    for (int jj = 0; jj < 4; jj++) {
      float4 t = *(const float4*)(wb + (size_t)jj * 4096 + k4 * 4);
      wr[jj][0] = t.x; wr[jj][1] = t.y; wr[jj][2] = t.z; wr[jj][3] = t.w;
    }
    #pragma unroll
    for (int c = 0; c < 4; c++) {
      float4 t = *(const float4*)(&xt[k4 * 4 + c][bg * 4]);
      xv[c][0] = t.x; xv[c][1] = t.y; xv[c][2] = t.z; xv[c][3] = t.w;
    }
    #pragma unroll
    for (int jj = 0; jj < 4; jj++)
      #pragma unroll
      for (int bb = 0; bb < 4; bb++)
        acc[jj][bb] += wr[jj][0] * xv[0][bb] + wr[jj][1] * xv[1][bb]
                     + wr[jj][2] * xv[2][bb] + wr[jj][3] * xv[3][bb];
  }
  #pragma unroll
  for (int jj = 0; jj < 4; jj++) {
    int col = colOff + jbase + jg * 4 + jj;
    #pragma unroll
    for (int bb = 0; bb < 4; bb++) {
      int b_ = bg * 4 + bb;
      part[((size_t)ks * 32 + b_) * ncols + col] = acc[jj][bb];
    }
  }
}

// ---------------------------------------------------------------------------
// Reduce split-K partials; apply RoPE to cols < ropeEnd.
// ---------------------------------------------------------------------------
__global__ __launch_bounds__(256) void reduce_rope_kernel(
    const float* __restrict__ part, int ncols,
    const float* __restrict__ cosv, const float* __restrict__ sinv,
    int ropeEnd, float* __restrict__ outb)
{
  int idx = blockIdx.x * 256 + threadIdx.x;
  int np = ncols >> 1;
  int b = idx / np;
  int cp = idx - b * np;
  int col = cp * 2;
  float e = 0.f, o = 0.f;
  #pragma unroll
  for (int ks = 0; ks < KSPLIT; ks++) {
    float2 v = *(const float2*)(part + ((size_t)ks * 32 + b) * ncols + col);
    e += v.x; o += v.y;
  }
  if (col < ropeEnd) {
    int fi = (col & 127) >> 1;
    float c = cosv[fi], s = sinv[fi];
    float ne = e * c - o * s;
    float no = e * s + o * c;
    e = ne; o = no;
  }
  *(float2*)(outb + (size_t)b * ncols + col) = make_float2(e, o);
}

// ---------------------------------------------------------------------------
// QK pass (bisection-verified vs naive): s_ws[b][h][t][r].
// 2048 blocks, 32 waves/CU. Row t == sp computed from RoPE'd new k.
// ---------------------------------------------------------------------------
__global__ __launch_bounds__(256, 8) void qk_kernel(
    const float* __restrict__ qkv,       // [32][6144]
    const float* __restrict__ cache_k,   // [32][2048][8][128]
    const int* __restrict__ spp,
    float* __restrict__ s_ws)            // [32][8][2048][4]
{
  int bid = blockIdx.x;
  int ts = bid & 7, h = (bid >> 3) & 7, b = bid >> 6;
  int sp = *spp;                              // 2047
  const float scale = 0.088388347648318447f;  // 1/sqrt(128)
  int tid = threadIdx.x;
  int wave = tid >> 6, lane = tid & 63;
  int tl = lane >> 5, dq = lane & 31;
  int tbase = ts * 256 + wave * 64;

  float4 qreg[4];
  {
    const float* qb = qkv + (size_t)b * 6144 + h * 512 + dq * 4;
    #pragma unroll
    for (int r = 0; r < 4; r++) {
      float4 q = *(const float4*)(qb + r * 128);
      qreg[r] = make_float4(q.x * scale, q.y * scale, q.z * scale, q.w * scale);
    }
  }
  const float* Krow = cache_k + (size_t)(b * 2048 + tbase + tl) * 1024 + h * 128 + dq * 4;
  float* srow = s_ws + (size_t)(b * 8 + h) * 8192;

  float4 buf[4];
  #pragma unroll
  for (int g = 0; g < 3; g++) buf[g] = *(const float4*)(Krow + (size_t)g * 2048);
  #pragma unroll 8
  for (int g = 0; g < 32; g++) {
    float4 kv = buf[g & 3];
    if (g + 3 < 32) buf[(g + 3) & 3] = *(const float4*)(Krow + (size_t)(g + 3) * 2048);
    float s0 = kv.x*qreg[0].x + kv.y*qreg[0].y + kv.z*qreg[0].z + kv.w*qreg[0].w;
    float s1 = kv.x*qreg[1].x + kv.y*qreg[1].y + kv.z*qreg[1].z + kv.w*qreg[1].w;
    float s2 = kv.x*qreg[2].x + kv.y*qreg[2].y + kv.z*qreg[2].z + kv.w*qreg[2].w;
    float s3 = kv.x*qreg[3].x + kv.y*qreg[3].y + kv.z*qreg[3].z + kv.w*qreg[3].w;
    #pragma unroll
    for (int off = 1; off <= 16; off <<= 1) {
      s0 += __shfl_xor(s0, off);
      s1 += __shfl_xor(s1, off);
      s2 += __shfl_xor(s2, off);
      s3 += __shfl_xor(s3, off);
    }
    int t = tbase + g * 2 + tl;
    if (dq == 0 && t != sp)
      *(float4*)(srow + (size_t)t * 4) = make_float4(s0, s1, s2, s3);
  }
  // new-token fixup: s[sp][r] = q[r] . k_new
  if (wave == 0 && (sp >> 8) == ts) {
    float4 kn4 = *(const float4*)(qkv + (size_t)b * 6144 + 4096 + h * 128 + dq * 4);
    float a[4];
    #pragma unroll
    for (int r = 0; r < 4; r++) {
      float a_ = kn4.x*qreg[r].x + kn4.y*qreg[r].y + kn4.z*qreg[r].z + kn4.w*qreg[r].w;
      #pragma unroll
      for (int off = 1; off <= 16; off <<= 1) a_ += __shfl_xor(a_, off);
      a[r] = a_;
    }
    if (lane == 0)
      *(float4*)(srow + (size_t)sp * 4) = make_float4(a[0], a[1], a[2], a[3]);
  }
}

// ---------------------------------------------------------------------------
// Softmax over t (bisection-verified vs naive). p = exp(s-m)/l in place.
// ---------------------------------------------------------------------------
__global__ __launch_bounds__(256) void softmax_kernel(float* __restrict__ s_ws)
{
  __shared__ float wred[4][4];
  int bh = blockIdx.x;                        // 0..255
  float* srow = s_ws + (size_t)bh * 8192;
  int tid = threadIdx.x, wave = tid >> 6, lane = tid & 63;
  float4 v[8];
  float pm[4] = {-INFINITY, -INFINITY, -INFINITY, -INFINITY};
  #pragma unroll
  for (int k = 0; k < 8; k++) {
    v[k] = *(const float4*)(srow + (size_t)(k * 256 + tid) * 4);
    pm[0] = fmaxf(pm[0], v[k].x); pm[1] = fmaxf(pm[1], v[k].y);
    pm[2] = fmaxf(pm[2], v[k].z); pm[3] = fmaxf(pm[3], v[k].w);
  }
  #pragma unroll
  for (int r = 0; r < 4; r++)
    #pragma unroll
    for (int off = 32; off >= 1; off >>= 1)
      pm[r] = fmaxf(pm[r], __shfl_xor(pm[r], off));
  if (lane == 0) {
    wred[wave][0] = pm[0]; wred[wave][1] = pm[1];
    wred[wave][2] = pm[2]; wred[wave][3] = pm[3];
  }
  __syncthreads();
  float m4[4];
  #pragma unroll
  for (int r = 0; r < 4; r++)
    m4[r] = fmaxf(fmaxf(wred[0][r], wred[1][r]), fmaxf(wred[2][r], wred[3][r]));
  __syncthreads();
  float ps[4] = {0.f, 0.f, 0.f, 0.f};
  #pragma unroll
  for (int k = 0; k < 8; k++) {
    v[k].x = __expf(v[k].x - m4[0]); ps[0] += v[k].x;
    v[k].y = __expf(v[k].y - m4[1]); ps[1] += v[k].y;
    v[k].z = __expf(v[k].z - m4[2]); ps[2] += v[k].z;
    v[k].w = __expf(v[k].w - m4[3]); ps[3] += v[k].w;
  }
  #pragma unroll
  for (int r = 0; r < 4; r++)
    #pragma unroll
    for (int off = 32; off >= 1; off >>= 1)
      ps[r] += __shfl_xor(ps[r], off);
  if (lane == 0) {
    wred[wave][0] = ps[0]; wred[wave][1] = ps[1];
    wred[wave][2] = ps[2]; wred[wave][3] = ps[3];
  }
  __syncthreads();
  float inv[4];
  #pragma unroll
  for (int r = 0; r < 4; r++)
    inv[r] = 1.f / (wred[0][r] + wred[1][r] + wred[2][r] + wred[3][r]);
  #pragma unroll
  for (int k = 0; k < 8; k++) {
    v[k].x *= inv[0]; v[k].y *= inv[1]; v[k].z *= inv[2]; v[k].w *= inv[3];
    *(float4*)(srow + (size_t)(k * 256 + tid) * 4) = v[k];
  }
}

// ---------------------------------------------------------------------------
// PV pass — FIXED: round 5/6 had all 4 waves racing on the same pv_part
// slice (no wave term in the index, no cross-wave reduce; bisection round 7
// showed probe_pv spinning while qk/sm probes passed). Now each wave
// publishes its partial to LDS red[wave][r][d]; after __syncthreads, thread
// (r,dp) sums the 4 waves and writes the final slice.
// ---------------------------------------------------------------------------
__global__ __launch_bounds__(256, 8) void pv_kernel(
    const float* __restrict__ p_ws,      // normalized p: [32][8][2048][4]
    const float* __restrict__ cache_v,   // [32][2048][8][128]
    const int* __restrict__ spp,
    float* __restrict__ pv_part)         // [8][32][8][4][128]
{
  __shared__ float red[4][4][128];       // [wave][r][d], 8 KB
  int bid = blockIdx.x;
  int ts = bid & 7, h = (bid >> 3) & 7, b = bid >> 6;
  int sp = *spp;
  int tid = threadIdx.x, wave = tid >> 6, lane = tid & 63;
  int half = lane >> 5, dq = lane & 31;
  int tbase = ts * 256 + wave * 64;
  const float* Vrow = cache_v + (size_t)(b * 2048 + tbase + half) * 1024 + h * 128 + dq * 4;
  const float* prow = p_ws + (size_t)(b * 8 + h) * 8192;

  float4 vbuf[4];
  #pragma unroll
  for (int g = 0; g < 3; g++) vbuf[g] = *(const float4*)(Vrow + (size_t)g * 2048);
  float o[4][4] = {};
  #pragma unroll 8
  for (int g = 0; g < 32; g++) {
    float4 vv = vbuf[g & 3];
    if (g + 3 < 32) vbuf[(g + 3) & 3] = *(const float4*)(Vrow + (size_t)(g + 3) * 2048);
    int t = tbase + g * 2 + half;
    float4 pp = *(const float4*)(prow + (size_t)t * 4);
    if (t == sp) pp = make_float4(0.f, 0.f, 0.f, 0.f);
    o[0][0] += pp.x * vv.x; o[0][1] += pp.x * vv.y;
    o[0][2] += pp.x * vv.z; o[0][3] += pp.x * vv.w;
    o[1][0] += pp.y * vv.x; o[1][1] += pp.y * vv.y;
    o[1][2] += pp.y * vv.z; o[1][3] += pp.y * vv.w;
    o[2][0] += pp.z * vv.x; o[2][1] += pp.z * vv.y;
    o[2][2] += pp.z * vv.z; o[2][3] += pp.z * vv.w;
    o[3][0] += pp.w * vv.x; o[3][1] += pp.w * vv.y;
    o[3][2] += pp.w * vv.z; o[3][3] += pp.w * vv.w;
  }
  // combine halves within the wave, publish per-wave partial to LDS
  #pragma unroll
  for (int r = 0; r < 4; r++)
    #pragma unroll
    for (int j = 0; j < 4; j++) o[r][j] += __shfl_xor(o[r][j], 32);
  if (half == 0) {
    #pragma unroll
    for (int r = 0; r < 4; r++)
      *(float4*)(&red[wave][r][dq * 4]) =
          make_float4(o[r][0], o[r][1], o[r][2], o[r][3]);
  }
  __syncthreads();
  // cross-wave reduce: thread (r, dp) sums 4 waves for d = dp*2, dp*2+1
  {
    int r = tid >> 6, dp = tid & 63;
    float a0 = red[0][r][dp * 2]     + red[1][r][dp * 2]
             + red[2][r][dp * 2]     + red[3][r][dp * 2];
    float a1 = red[0][r][dp * 2 + 1] + red[1][r][dp * 2 + 1]
             + red[2][r][dp * 2 + 1] + red[3][r][dp * 2 + 1];
    float* pb = pv_part + (size_t)(((ts * 32 + b) * 8 + h) * 4 + r) * 128;
    *(float2*)(pb + dp * 2) = make_float2(a0, a1);
  }
}

// ---------------------------------------------------------------------------
// Combine the 8 t-split partials and add the new-token term p[sp]*v_new.
// ---------------------------------------------------------------------------
__global__ __launch_bounds__(256) void pv_combine_kernel(
    const float* __restrict__ pv_part,
    const float* __restrict__ p_ws,
    const float* __restrict__ qkv,
    const int* __restrict__ spp,
    float* __restrict__ attn)
{
  int idx = blockIdx.x * 256 + threadIdx.x;   // 131072 = 32*8*4*128
  int d = idx & 127;
  int r = (idx >> 7) & 3;
  int h = (idx >> 9) & 7;
  int b = idx >> 12;
  float acc = 0.f;
  #pragma unroll
  for (int ts = 0; ts < 8; ts++)
    acc += pv_part[(size_t)(((ts * 32 + b) * 8 + h) * 4 + r) * 128 + d];
  int sp = *spp;
  float psp = p_ws[(size_t)(b * 8 + h) * 8192 + (size_t)sp * 4 + r];
  float vn  = qkv[(size_t)b * 6144 + 5120 + h * 128 + d];
  attn[idx] = acc + psp * vn;                 // idx == b*4096 + (h*4+r)*128 + d
}

extern "C" void kernel_launch(void* const* d_in, const int* in_sizes, int n_in,
                              void* d_out, int out_size, void* d_ws, size_t ws_size,
                              hipStream_t stream)
{
  const float* x   = (const float*)d_in[0];
  const float* wq  = (const float*)d_in[1];
  const float* wk  = (const float*)d_in[2];
  const float* wv  = (const float*)d_in[3];
  const float* wo  = (const float*)d_in[4];
  const float* fc  = (const float*)d_in[5];
  const float* fs  = (const float*)d_in[6];
  const float* ck  = (const float*)d_in[7];
  const float* cv  = (const float*)d_in[8];
  const int*   spp = (const int*)d_in[9];
  float* out = (float*)d_out;

  // Workspace layout with lifetime-based aliasing (13.9 MB high-water):
  //   region A [0 .. 3,145,728):
  //     qkv_part [16][32][6144]     live L1-L2
  //     s_ws     [32][8][2048][4]   live L3-L6 (A + 0)
  //     pv_part  [8][32][8][4][128] live L5-L6 (A + 2,097,152)
  //     out_part [16][32][4096]     live L7-L8 (A + 0)
  //   qkvbuf  at 3,145,728 (196,608 f)  live L2-L6
  //   attnbuf at 3,342,336 (131,072 f)  live L6-L7
  float* ws = (float*)d_ws;
  float* qkv_part  = ws;
  float* s_ws      = ws;
  float* pv_part   = ws + 2097152;
  float* out_part  = ws;
  float* qkvbuf    = ws + 3145728;
  float* attnbuf   = ws + 3342336;

  // L1: QKV projections (fused, split-K)
  gemv_part_kernel<<<dim3(48, KSPLIT), 256, 0, stream>>>(
      x, wq, wk, wv, 32, 40, 0, 4096, 5120, 6144, qkv_part);
  // L2: reduce + RoPE (q and k rotated, v passthrough)
  reduce_rope_kernel<<<384, 256, 0, stream>>>(qkv_part, 6144, fc, fs, 5120, qkvbuf);
  // L3-L6: attention: QK -> softmax -> PV -> combine
  qk_kernel<<<2048, 256, 0, stream>>>(qkvbuf, ck, spp, s_ws);
  softmax_kernel<<<256, 256, 0, stream>>>(s_ws);
  pv_kernel<<<2048, 256, 0, stream>>>(s_ws, cv, spp, pv_part);
  pv_combine_kernel<<<512, 256, 0, stream>>>(pv_part, s_ws, qkvbuf, spp, attnbuf);
  // L7: output projection (split-K)
  gemv_part_kernel<<<dim3(32, KSPLIT), 256, 0, stream>>>(
      attnbuf, wo, wo, wo, 32, 32, 0, 0, 0, 4096, out_part);
  // L8: final reduce
  reduce_rope_kernel<<<256, 256, 0, stream>>>(out_part, 4096, fc, fs, 0, out);
}

// Round 9
// 221.710 us; speedup vs baseline: 51.7725x; 1.6246x over previous
//
#include <hip/hip_runtime.h>
#include <hip/hip_bf16.h>
#include <math.h>

#define KSPLIT 16
#define KCHUNK 256
#define BJ 128

// ---------------------------------------------------------------------------
// Split-K batched GEMV: part[ks][b][col] = sum_{k in chunk ks} x[b][k]*w[col][k]
// ---------------------------------------------------------------------------
__global__ __launch_bounds__(256) void gemv_part_kernel(
    const float* __restrict__ x,
    const float* __restrict__ w0,
    const float* __restrict__ w1,
    const float* __restrict__ w2,
    int jb1, int jb2,
    int off0, int off1, int off2,
    int ncols,
    float* __restrict__ part)
{
  __shared__ float xt[KCHUNK][32];
  int jb = blockIdx.x, ks = blockIdx.y;
  int k0 = ks * KCHUNK;
  const float* w; int colOff, jbase;
  if (jb < jb1)      { w = w0; colOff = off0; jbase = jb * BJ; }
  else if (jb < jb2) { w = w1; colOff = off1; jbase = (jb - jb1) * BJ; }
  else               { w = w2; colOff = off2; jbase = (jb - jb2) * BJ; }
  int tid = threadIdx.x;
  {
    int b = tid & 31, kg = tid >> 5;
    const float* xr = x + (size_t)b * 4096 + k0 + kg * 32;
    #pragma unroll
    for (int i = 0; i < 8; i++) {
      float4 v = *(const float4*)(xr + i * 4);
      int k = kg * 32 + i * 4;
      xt[k + 0][b] = v.x; xt[k + 1][b] = v.y;
      xt[k + 2][b] = v.z; xt[k + 3][b] = v.w;
    }
  }
  __syncthreads();
  int bg = tid & 7, jg = tid >> 3;
  const float* wb = w + (size_t)(jbase + jg * 4) * 4096 + k0;
  float acc[4][4] = {};
  #pragma unroll 4
  for (int k4 = 0; k4 < KCHUNK / 4; k4++) {
    float wr[4][4], xv[4][4];
    #pragma unroll
    for (int jj = 0; jj < 4; jj++) {
      float4 t = *(const float4*)(wb + (size_t)jj * 4096 + k4 * 4);
      wr[jj][0] = t.x; wr[jj][1] = t.y; wr[jj][2] = t.z; wr[jj][3] = t.w;
    }
    #pragma unroll
    for (int c = 0; c < 4; c++) {
      float4 t = *(const float4*)(&xt[k4 * 4 + c][bg * 4]);
      xv[c][0] = t.x; xv[c][1] = t.y; xv[c][2] = t.z; xv[c][3] = t.w;
    }
    #pragma unroll
    for (int jj = 0; jj < 4; jj++)
      #pragma unroll
      for (int bb = 0; bb < 4; bb++)
        acc[jj][bb] += wr[jj][0] * xv[0][bb] + wr[jj][1] * xv[1][bb]
                     + wr[jj][2] * xv[2][bb] + wr[jj][3] * xv[3][bb];
  }
  #pragma unroll
  for (int jj = 0; jj < 4; jj++) {
    int col = colOff + jbase + jg * 4 + jj;
    #pragma unroll
    for (int bb = 0; bb < 4; bb++) {
      int b_ = bg * 4 + bb;
      part[((size_t)ks * 32 + b_) * ncols + col] = acc[jj][bb];
    }
  }
}

// ---------------------------------------------------------------------------
// Reduce split-K partials; apply RoPE to cols < ropeEnd.
// ---------------------------------------------------------------------------
__global__ __launch_bounds__(256) void reduce_rope_kernel(
    const float* __restrict__ part, int ncols,
    const float* __restrict__ cosv, const float* __restrict__ sinv,
    int ropeEnd, float* __restrict__ outb)
{
  int idx = blockIdx.x * 256 + threadIdx.x;
  int np = ncols >> 1;
  int b = idx / np;
  int cp = idx - b * np;
  int col = cp * 2;
  float e = 0.f, o = 0.f;
  #pragma unroll
  for (int ks = 0; ks < KSPLIT; ks++) {
    float2 v = *(const float2*)(part + ((size_t)ks * 32 + b) * ncols + col);
    e += v.x; o += v.y;
  }
  if (col < ropeEnd) {
    int fi = (col & 127) >> 1;
    float c = cosv[fi], s = sinv[fi];
    float ne = e * c - o * s;
    float no = e * s + o * c;
    e = ne; o = no;
  }
  *(float2*)(outb + (size_t)b * ncols + col) = make_float2(e, o);
}

// ---------------------------------------------------------------------------
// QK pass (bisection-verified). FIXED vs round 8: the 32-iter loop is now
// FULLY unrolled so the prefetch ring index (g & 3) is compile-time static.
// Round 8's "#pragma unroll 8" left g runtime -> buf[] allocated in scratch
// (HBM!) -> ~256 MB of hidden spill traffic (rule #20; VGPR_Count=32 was the
// tell). launch_bounds min-waves relaxed to 4 so live regs can't be forced
// to spill again.
// ---------------------------------------------------------------------------
__global__ __launch_bounds__(256, 4) void qk_kernel(
    const float* __restrict__ qkv,       // [32][6144]
    const float* __restrict__ cache_k,   // [32][2048][8][128]
    const int* __restrict__ spp,
    float* __restrict__ s_ws)            // [32][8][2048][4]
{
  int bid = blockIdx.x;
  int ts = bid & 7, h = (bid >> 3) & 7, b = bid >> 6;
  int sp = *spp;                              // 2047
  const float scale = 0.088388347648318447f;  // 1/sqrt(128)
  int tid = threadIdx.x;
  int wave = tid >> 6, lane = tid & 63;
  int tl = lane >> 5, dq = lane & 31;
  int tbase = ts * 256 + wave * 64;

  float4 qreg[4];
  {
    const float* qb = qkv + (size_t)b * 6144 + h * 512 + dq * 4;
    #pragma unroll
    for (int r = 0; r < 4; r++) {
      float4 q = *(const float4*)(qb + r * 128);
      qreg[r] = make_float4(q.x * scale, q.y * scale, q.z * scale, q.w * scale);
    }
  }
  const float* Krow = cache_k + (size_t)(b * 2048 + tbase + tl) * 1024 + h * 128 + dq * 4;
  float* srow = s_ws + (size_t)(b * 8 + h) * 8192;

  float4 buf[4];
  #pragma unroll
  for (int g = 0; g < 3; g++) buf[g] = *(const float4*)(Krow + (size_t)g * 2048);
  #pragma unroll
  for (int g = 0; g < 32; g++) {              // FULL unroll: g static
    float4 kv = buf[g & 3];
    if (g + 3 < 32) buf[(g + 3) & 3] = *(const float4*)(Krow + (size_t)(g + 3) * 2048);
    float s0 = kv.x*qreg[0].x + kv.y*qreg[0].y + kv.z*qreg[0].z + kv.w*qreg[0].w;
    float s1 = kv.x*qreg[1].x + kv.y*qreg[1].y + kv.z*qreg[1].z + kv.w*qreg[1].w;
    float s2 = kv.x*qreg[2].x + kv.y*qreg[2].y + kv.z*qreg[2].z + kv.w*qreg[2].w;
    float s3 = kv.x*qreg[3].x + kv.y*qreg[3].y + kv.z*qreg[3].z + kv.w*qreg[3].w;
    #pragma unroll
    for (int off = 1; off <= 16; off <<= 1) {
      s0 += __shfl_xor(s0, off);
      s1 += __shfl_xor(s1, off);
      s2 += __shfl_xor(s2, off);
      s3 += __shfl_xor(s3, off);
    }
    int t = tbase + g * 2 + tl;
    if (dq == 0 && t != sp)
      *(float4*)(srow + (size_t)t * 4) = make_float4(s0, s1, s2, s3);
  }
  // new-token fixup: s[sp][r] = q[r] . k_new
  if (wave == 0 && (sp >> 8) == ts) {
    float4 kn4 = *(const float4*)(qkv + (size_t)b * 6144 + 4096 + h * 128 + dq * 4);
    float a[4];
    #pragma unroll
    for (int r = 0; r < 4; r++) {
      float a_ = kn4.x*qreg[r].x + kn4.y*qreg[r].y + kn4.z*qreg[r].z + kn4.w*qreg[r].w;
      #pragma unroll
      for (int off = 1; off <= 16; off <<= 1) a_ += __shfl_xor(a_, off);
      a[r] = a_;
    }
    if (lane == 0)
      *(float4*)(srow + (size_t)sp * 4) = make_float4(a[0], a[1], a[2], a[3]);
  }
}

// ---------------------------------------------------------------------------
// Softmax over t (bisection-verified). p = exp(s-m)/l in place.
// ---------------------------------------------------------------------------
__global__ __launch_bounds__(256) void softmax_kernel(float* __restrict__ s_ws)
{
  __shared__ float wred[4][4];
  int bh = blockIdx.x;                        // 0..255
  float* srow = s_ws + (size_t)bh * 8192;
  int tid = threadIdx.x, wave = tid >> 6, lane = tid & 63;
  float4 v[8];
  float pm[4] = {-INFINITY, -INFINITY, -INFINITY, -INFINITY};
  #pragma unroll
  for (int k = 0; k < 8; k++) {
    v[k] = *(const float4*)(srow + (size_t)(k * 256 + tid) * 4);
    pm[0] = fmaxf(pm[0], v[k].x); pm[1] = fmaxf(pm[1], v[k].y);
    pm[2] = fmaxf(pm[2], v[k].z); pm[3] = fmaxf(pm[3], v[k].w);
  }
  #pragma unroll
  for (int r = 0; r < 4; r++)
    #pragma unroll
    for (int off = 32; off >= 1; off >>= 1)
      pm[r] = fmaxf(pm[r], __shfl_xor(pm[r], off));
  if (lane == 0) {
    wred[wave][0] = pm[0]; wred[wave][1] = pm[1];
    wred[wave][2] = pm[2]; wred[wave][3] = pm[3];
  }
  __syncthreads();
  float m4[4];
  #pragma unroll
  for (int r = 0; r < 4; r++)
    m4[r] = fmaxf(fmaxf(wred[0][r], wred[1][r]), fmaxf(wred[2][r], wred[3][r]));
  __syncthreads();
  float ps[4] = {0.f, 0.f, 0.f, 0.f};
  #pragma unroll
  for (int k = 0; k < 8; k++) {
    v[k].x = __expf(v[k].x - m4[0]); ps[0] += v[k].x;
    v[k].y = __expf(v[k].y - m4[1]); ps[1] += v[k].y;
    v[k].z = __expf(v[k].z - m4[2]); ps[2] += v[k].z;
    v[k].w = __expf(v[k].w - m4[3]); ps[3] += v[k].w;
  }
  #pragma unroll
  for (int r = 0; r < 4; r++)
    #pragma unroll
    for (int off = 32; off >= 1; off >>= 1)
      ps[r] += __shfl_xor(ps[r], off);
  if (lane == 0) {
    wred[wave][0] = ps[0]; wred[wave][1] = ps[1];
    wred[wave][2] = ps[2]; wred[wave][3] = ps[3];
  }
  __syncthreads();
  float inv[4];
  #pragma unroll
  for (int r = 0; r < 4; r++)
    inv[r] = 1.f / (wred[0][r] + wred[1][r] + wred[2][r] + wred[3][r]);
  #pragma unroll
  for (int k = 0; k < 8; k++) {
    v[k].x *= inv[0]; v[k].y *= inv[1]; v[k].z *= inv[2]; v[k].w *= inv[3];
    *(float4*)(srow + (size_t)(k * 256 + tid) * 4) = v[k];
  }
}

// ---------------------------------------------------------------------------
// PV pass (race fixed in r8 via LDS cross-wave reduce). FIXED vs round 8:
// full unroll of the 32-iter loop -> static ring index, no scratch spill.
// ---------------------------------------------------------------------------
__global__ __launch_bounds__(256, 4) void pv_kernel(
    const float* __restrict__ p_ws,      // normalized p: [32][8][2048][4]
    const float* __restrict__ cache_v,   // [32][2048][8][128]
    const int* __restrict__ spp,
    float* __restrict__ pv_part)         // [8][32][8][4][128]
{
  __shared__ float red[4][4][128];       // [wave][r][d], 8 KB
  int bid = blockIdx.x;
  int ts = bid & 7, h = (bid >> 3) & 7, b = bid >> 6;
  int sp = *spp;
  int tid = threadIdx.x, wave = tid >> 6, lane = tid & 63;
  int half = lane >> 5, dq = lane & 31;
  int tbase = ts * 256 + wave * 64;
  const float* Vrow = cache_v + (size_t)(b * 2048 + tbase + half) * 1024 + h * 128 + dq * 4;
  const float* prow = p_ws + (size_t)(b * 8 + h) * 8192;

  float4 vbuf[4];
  #pragma unroll
  for (int g = 0; g < 3; g++) vbuf[g] = *(const float4*)(Vrow + (size_t)g * 2048);
  float o[4][4] = {};
  #pragma unroll
  for (int g = 0; g < 32; g++) {              // FULL unroll: g static
    float4 vv = vbuf[g & 3];
    if (g + 3 < 32) vbuf[(g + 3) & 3] = *(const float4*)(Vrow + (size_t)(g + 3) * 2048);
    int t = tbase + g * 2 + half;
    float4 pp = *(const float4*)(prow + (size_t)t * 4);
    if (t == sp) pp = make_float4(0.f, 0.f, 0.f, 0.f);
    o[0][0] += pp.x * vv.x; o[0][1] += pp.x * vv.y;
    o[0][2] += pp.x * vv.z; o[0][3] += pp.x * vv.w;
    o[1][0] += pp.y * vv.x; o[1][1] += pp.y * vv.y;
    o[1][2] += pp.y * vv.z; o[1][3] += pp.y * vv.w;
    o[2][0] += pp.z * vv.x; o[2][1] += pp.z * vv.y;
    o[2][2] += pp.z * vv.z; o[2][3] += pp.z * vv.w;
    o[3][0] += pp.w * vv.x; o[3][1] += pp.w * vv.y;
    o[3][2] += pp.w * vv.z; o[3][3] += pp.w * vv.w;
  }
  // combine halves within the wave, publish per-wave partial to LDS
  #pragma unroll
  for (int r = 0; r < 4; r++)
    #pragma unroll
    for (int j = 0; j < 4; j++) o[r][j] += __shfl_xor(o[r][j], 32);
  if (half == 0) {
    #pragma unroll
    for (int r = 0; r < 4; r++)
      *(float4*)(&red[wave][r][dq * 4]) =
          make_float4(o[r][0], o[r][1], o[r][2], o[r][3]);
  }
  __syncthreads();
  // cross-wave reduce: thread (r, dp) sums 4 waves for d = dp*2, dp*2+1
  {
    int r = tid >> 6, dp = tid & 63;
    float a0 = red[0][r][dp * 2]     + red[1][r][dp * 2]
             + red[2][r][dp * 2]     + red[3][r][dp * 2];
    float a1 = red[0][r][dp * 2 + 1] + red[1][r][dp * 2 + 1]
             + red[2][r][dp * 2 + 1] + red[3][r][dp * 2 + 1];
    float* pb = pv_part + (size_t)(((ts * 32 + b) * 8 + h) * 4 + r) * 128;
    *(float2*)(pb + dp * 2) = make_float2(a0, a1);
  }
}

// ---------------------------------------------------------------------------
// Combine the 8 t-split partials and add the new-token term p[sp]*v_new.
// ---------------------------------------------------------------------------
__global__ __launch_bounds__(256) void pv_combine_kernel(
    const float* __restrict__ pv_part,
    const float* __restrict__ p_ws,
    const float* __restrict__ qkv,
    const int* __restrict__ spp,
    float* __restrict__ attn)
{
  int idx = blockIdx.x * 256 + threadIdx.x;   // 131072 = 32*8*4*128
  int d = idx & 127;
  int r = (idx >> 7) & 3;
  int h = (idx >> 9) & 7;
  int b = idx >> 12;
  float acc = 0.f;
  #pragma unroll
  for (int ts = 0; ts < 8; ts++)
    acc += pv_part[(size_t)(((ts * 32 + b) * 8 + h) * 4 + r) * 128 + d];
  int sp = *spp;
  float psp = p_ws[(size_t)(b * 8 + h) * 8192 + (size_t)sp * 4 + r];
  float vn  = qkv[(size_t)b * 6144 + 5120 + h * 128 + d];
  attn[idx] = acc + psp * vn;                 // idx == b*4096 + (h*4+r)*128 + d
}

extern "C" void kernel_launch(void* const* d_in, const int* in_sizes, int n_in,
                              void* d_out, int out_size, void* d_ws, size_t ws_size,
                              hipStream_t stream)
{
  const float* x   = (const float*)d_in[0];
  const float* wq  = (const float*)d_in[1];
  const float* wk  = (const float*)d_in[2];
  const float* wv  = (const float*)d_in[3];
  const float* wo  = (const float*)d_in[4];
  const float* fc  = (const float*)d_in[5];
  const float* fs  = (const float*)d_in[6];
  const float* ck  = (const float*)d_in[7];
  const float* cv  = (const float*)d_in[8];
  const int*   spp = (const int*)d_in[9];
  float* out = (float*)d_out;

  // Workspace layout with lifetime-based aliasing (13.9 MB high-water):
  //   region A [0 .. 3,145,728):
  //     qkv_part [16][32][6144]     live L1-L2
  //     s_ws     [32][8][2048][4]   live L3-L6 (A + 0)
  //     pv_part  [8][32][8][4][128] live L5-L6 (A + 2,097,152)
  //     out_part [16][32][4096]     live L7-L8 (A + 0)
  //   qkvbuf  at 3,145,728 (196,608 f)  live L2-L6
  //   attnbuf at 3,342,336 (131,072 f)  live L6-L7
  float* ws = (float*)d_ws;
  float* qkv_part  = ws;
  float* s_ws      = ws;
  float* pv_part   = ws + 2097152;
  float* out_part  = ws;
  float* qkvbuf    = ws + 3145728;
  float* attnbuf   = ws + 3342336;

  // L1: QKV projections (fused, split-K)
  gemv_part_kernel<<<dim3(48, KSPLIT), 256, 0, stream>>>(
      x, wq, wk, wv, 32, 40, 0, 4096, 5120, 6144, qkv_part);
  // L2: reduce + RoPE (q and k rotated, v passthrough)
  reduce_rope_kernel<<<384, 256, 0, stream>>>(qkv_part, 6144, fc, fs, 5120, qkvbuf);
  // L3-L6: attention: QK -> softmax -> PV -> combine
  qk_kernel<<<2048, 256, 0, stream>>>(qkvbuf, ck, spp, s_ws);
  softmax_kernel<<<256, 256, 0, stream>>>(s_ws);
  pv_kernel<<<2048, 256, 0, stream>>>(s_ws, cv, spp, pv_part);
  pv_combine_kernel<<<512, 256, 0, stream>>>(pv_part, s_ws, qkvbuf, spp, attnbuf);
  // L7: output projection (split-K)
  gemv_part_kernel<<<dim3(32, KSPLIT), 256, 0, stream>>>(
      attnbuf, wo, wo, wo, 32, 32, 0, 0, 0, 4096, out_part);
  // L8: final reduce
  reduce_rope_kernel<<<256, 256, 0, stream>>>(out_part, 4096, fc, fs, 0, out);
}